// Round 22
// baseline (407.035 us; speedup 1.0000x reference)
//
#include <hip/hip_runtime.h>

typedef __attribute__((ext_vector_type(4))) float f32x4_t;
typedef __attribute__((ext_vector_type(8))) short bf16x8_t;

#define NROWS 16384
#define NCODES 4096
#define DIM 512
#define DELTA 0.005f     // > worst-case |f64 referee - hi-only bf16 pass1| = 0.0040
#define MAXC 16          // explicit candidate cap per row (overflow -> group bit)

// ---------------- workspace byte offsets (~41.5 MB; harness provides >=45.6 MB, proven round 4) ----------------
#define WS_A      0u          // 128 tb x 8 st x 16KB (BK=64 stages) -> 16777216
#define WS_B      16777216u   //  32 ct x 8 st x 16KB -> 20971520
#define WS_TOPE   20971520u   // [row 16384][grp 64] float4 -> 37748736
#define WS_COUNTS 37748736u   // 4096 u32 -> 37765120
#define WS_FLAGS  37765120u   // [0]=mask-layout [1]=item_cnt -> +64
#define WS_IDX    37765184u   // 16384 i32 -> 37830720
#define WS_ITEMS  37830720u   // 16384 x 20 i32 {row,cnt,maskLo,maskHi,cid[16]} -> 39141440
#define WS_CPART  39206976u   // 4096 f64 -> 39239744
#define WS_GPART  39239744u   // 16384 x 8 double2 -> 41336896
#define WS_ITEMOF 41336896u   // 16384 i32 -> 41402432

// output element offsets (flat f32)
#define OUT_ZQ      0
#define OUT_ZQST    8388608
#define OUT_IDX     16777216
#define OUT_VQ      16793600
#define OUT_COMMIT  16793601
#define OUT_PERP    16793602

__device__ __forceinline__ unsigned short f2bf(float x) {
  unsigned u = __builtin_bit_cast(unsigned, x);
  unsigned r = (u + 0x7FFFu + ((u >> 16) & 1u)) >> 16;  // RNE
  return (unsigned short)r;
}
__device__ __forceinline__ unsigned hz(unsigned x) {
  return (x - 0x01010101u) & ~x & 0x80808080u;  // any zero byte
}
// BK=64 stage layout: row r in [0,128) is 128B (8 x 16B units); XOR keeps ds_read banks 2-way (free)
__device__ __forceinline__ unsigned swz64(int r, int u) {
  return (unsigned)(r * 128 + ((u ^ (r & 7)) << 4));
}
// group g (0..63) -> base code; within-group offset o (0..63) -> code
__device__ __forceinline__ int grp_base(int g) {
  return (g >> 3) * 512 + ((g >> 2) & 1) * 64 + (g & 3) * 4;  // cg*512 + wc*64 + lrg*4
}
__device__ __forceinline__ int grp_code(int cbase, int o) {
  return cbase + (o >> 4) * 128 + ((o >> 2) & 3) * 16 + (o & 3);  // + ct*128 + n*16 + l
}

// ---------------- prep: zero counts/flags + mask probe + norms + bf16-hi convert into swizzled chunks ----------------
__global__ void prep_kernel(const float* __restrict__ z, const float* __restrict__ cb,
                            const uint4* __restrict__ mk,
                            unsigned char* __restrict__ Aws, unsigned char* __restrict__ Bws,
                            unsigned* __restrict__ counts, unsigned* __restrict__ flags) {
  if (blockIdx.x < 16) {
    counts[blockIdx.x * 256 + threadIdx.x] = 0;  // 4096 counts
  }
  if (blockIdx.x == 0) {
    if (threadIdx.x < 4) flags[threadIdx.x] = 0;
    __syncthreads();
    unsigned f = 0;
    for (int i = threadIdx.x; i < 1024; i += 256) {  // first 16KB of mask
      uint4 v = mk[i];
      f |= hz(v.x) | hz(v.y) | hz(v.z) | hz(v.w);
    }
    if (f) atomicOr(&flags[0], 1u);  // zero byte found -> int32 mask layout
  }
  const int wv = threadIdx.x >> 6, lane = threadIdx.x & 63;
  const int row = blockIdx.x * 4 + wv;
  if (row >= NROWS + NCODES) return;
  const bool isA = row < NROWS;
  const int lrow = isA ? row : row - NROWS;
  const float* src = (isA ? z : cb) + (size_t)lrow * DIM;
  f32x4_t a = *(const f32x4_t*)(src + lane * 8);
  f32x4_t b = *(const f32x4_t*)(src + lane * 8 + 4);
  double s = 0.0;
#pragma unroll
  for (int e = 0; e < 4; ++e) s += (double)a[e] * a[e] + (double)b[e] * b[e];
#pragma unroll
  for (int off = 1; off < 64; off <<= 1) s += __shfl_xor(s, off);
  const float inv = (float)(1.0 / fmax(sqrt(s), 1e-8));
  union { unsigned short u[8]; uint4 v; } H;
#pragma unroll
  for (int e = 0; e < 4; ++e) {
    H.u[e] = f2bf(a[e] * inv);
    H.u[4 + e] = f2bf(b[e] * inv);
  }
  const int tb = lrow >> 7, rr = lrow & 127;
  const int st = lane >> 3, u = lane & 7;  // stage = 64 cols, unit = 8 cols
  unsigned char* chunk = (isA ? Aws : Bws) + ((size_t)tb * 8 + st) * 16384;
  *(uint4*)(chunk + swz64(rr, u)) = H.v;
}

// ---------------- pass-1 GEMM: BK=64 single-buffer; per-lane top-2 + LDS-staged coalesced topE write ----------------
__global__ __launch_bounds__(256, 5) void gemm_p1_kernel(
    const unsigned char* __restrict__ Aws, const unsigned char* __restrict__ Bws,
    float4* __restrict__ topE) {
  __align__(16) __shared__ unsigned char smem[32768];  // staging (A 16K | B 16K); reused for topE stage

  const int tid = threadIdx.x;
  const int bid = blockIdx.x;
  const int xcd = bid & 7, q0 = bid >> 3;
  const int rb = xcd * 16 + (q0 >> 3), cg = q0 & 7;  // XCD-aware: 8 cg-blocks of one rb share an XCD L2
  const int wave = tid >> 6, lane = tid & 63;
  const int wr = wave >> 1, wc = wave & 1;
  const int kg = lane >> 4, lr = lane & 15;

  const unsigned char* Ach = Aws + (size_t)rb * 8 * 16384;

  auto issue_stage = [&](const unsigned char* Asrc, const unsigned char* Bsrc) {
#pragma unroll
    for (int i = 0; i < 8; ++i) {
      const int j = wave * 8 + i;  // 32 x 1KB units: A 0-15 -> lds 0-16K, B 16-31 -> lds 16-32K
      const unsigned char* sp = (j < 16) ? (Asrc + (size_t)j * 1024 + lane * 16)
                                         : (Bsrc + (size_t)(j - 16) * 1024 + lane * 16);
      __builtin_amdgcn_global_load_lds(
          (const __attribute__((address_space(1))) void*)sp,
          (__attribute__((address_space(3))) void*)(smem + j * 1024), 16, 0, 0);
    }
  };

  // per-lane running top-2 over the lane's 16 codes per (m,j): 48 VGPRs, static indexing only
  float tv1[16], tv2[16]; int ti1[16];
#pragma unroll
  for (int q = 0; q < 16; ++q) { tv1[q] = -3e38f; tv2[q] = -3e38f; ti1[q] = 0; }

  for (int ct = 0; ct < 4; ++ct) {
    const int ctile = cg * 4 + ct;
    const int code0 = ctile * 128;
    const unsigned char* Bch = Bws + (size_t)ctile * 8 * 16384;

    f32x4_t acc[4][4];
#pragma unroll
    for (int m = 0; m < 4; ++m)
#pragma unroll
      for (int n = 0; n < 4; ++n) acc[m][n] = (f32x4_t){0.f, 0.f, 0.f, 0.f};

    for (int st = 0; st < 8; ++st) {
      if (!(st == 0 && ct > 0))  // ct>0 stage-0 was pre-issued before previous insertion block
        issue_stage(Ach + (size_t)st * 16384, Bch + (size_t)st * 16384);
      __syncthreads();  // compiler drains vmcnt before barrier (m97 pattern)

#pragma unroll
      for (int kk = 0; kk < 2; ++kk) {  // two 32-col halves; frags scoped to stay in budget
        bf16x8_t ah[4], bh[4];
        const int u = kk * 4 + kg;
#pragma unroll
        for (int m = 0; m < 4; ++m) {
          const int r = wr * 64 + m * 16 + lr;
          ah[m] = *(const bf16x8_t*)(smem + swz64(r, u));
        }
#pragma unroll
        for (int n = 0; n < 4; ++n) {
          const int r = wc * 64 + n * 16 + lr;
          bh[n] = *(const bf16x8_t*)(smem + 16384 + swz64(r, u));
        }
#pragma unroll
        for (int m = 0; m < 4; ++m)
#pragma unroll
          for (int n = 0; n < 4; ++n)
            acc[m][n] = __builtin_amdgcn_mfma_f32_16x16x32_bf16(ah[m], bh[n], acc[m][n], 0, 0, 0);
      }
      __syncthreads();  // reads done before next stage overwrites
    }

    // pre-issue next ct's first stage: latency hides under the insertion block below
    if (ct < 3)
      issue_stage(Ach, Bws + (size_t)(ctile + 1) * 8 * 16384);

    // cheap per-lane insertion (no shuffles, no barriers): ascending code order keeps np ties
#pragma unroll
    for (int m = 0; m < 4; ++m)
#pragma unroll
      for (int j = 0; j < 4; ++j) {
        const int q = m * 4 + j;
#pragma unroll
        for (int n = 0; n < 4; ++n) {
          float v = acc[m][n][j];
          int gc = code0 + wc * 64 + n * 16 + lr;
          if (v > tv1[q]) { tv2[q] = tv1[q]; tv1[q] = v; ti1[q] = gc; }
          else if (v > tv2[q]) tv2[q] = v;
        }
      }
  }

  // single 2-step butterfly -> exact top-2 per (row, cg, wc, lr>>2); stage into LDS (smem is dead now)
  float4* stop = (float4*)smem;  // [lrow 128][e 8] = 16KB
#pragma unroll
  for (int m = 0; m < 4; ++m)
#pragma unroll
    for (int j = 0; j < 4; ++j) {
      const int q = m * 4 + j;
      float v1 = tv1[q], v2 = tv2[q]; int i1 = ti1[q];
#pragma unroll
      for (int mask = 1; mask <= 2; mask <<= 1) {
        float ov1 = __shfl_xor(v1, mask); int oi1 = __shfl_xor(i1, mask);
        float ov2 = __shfl_xor(v2, mask);
        bool of = (ov1 > v1) || (ov1 == v1 && oi1 < i1);
        float w1 = of ? ov1 : v1;  int k1 = of ? oi1 : i1;
        float lv = of ? v1 : ov1;  // loser's top-1
        float sv = of ? ov2 : v2;  // winner's top-2
        v1 = w1; i1 = k1;
        v2 = (lv > sv) ? lv : sv;  // v2 magnitude only (bounds unreported codes)
      }
      if ((lr & 3) == 0) {
        const int lrow = wr * 64 + m * 16 + kg * 4 + j;
        stop[lrow * 8 + wc * 4 + (lr >> 2)] =
            make_float4(v1, __builtin_bit_cast(float, i1), v2, 0.f);
      }
    }
  __syncthreads();
  // coalesced copy: 1024 float4 entries; thread t writes 4 consecutive (64B) -> full-line stores
#pragma unroll
  for (int i = 0; i < 4; ++i) {
    const int idx = tid * 4 + i;
    const int lrow = idx >> 3, e = idx & 7;
    topE[(size_t)(rb * 128 + lrow) * 64 + cg * 8 + e] = stop[idx];
  }
}

// ---------------- resolve: classify rows into {direct, referee item} (thread per row) ----------------
__global__ void resolve_kernel(const float4* __restrict__ topE, int* __restrict__ idxf,
                               int* __restrict__ items, int* __restrict__ itemOf,
                               unsigned* __restrict__ flags) {
  const int row = blockIdx.x * 256 + threadIdx.x;
  if (row >= NROWS) return;
  const float4* e = topE + (size_t)row * 64;
  float V1 = -3e38f; int I1 = 1 << 30;
  for (int g = 0; g < 64; ++g) {  // groups not code-ascending -> explicit index tie-break (np)
    float4 qv = e[g];
    const int i = __builtin_bit_cast(int, qv.y);
    if (qv.x > V1 || (qv.x == V1 && i < I1)) { V1 = qv.x; I1 = i; }
  }
  const float T = V1 - 2.0f * DELTA;
  unsigned long long smask = 0ull;  // suspect groups: their top-2 may hide a 3rd candidate
  int cnt = 0; int cid[MAXC];
  for (int g = 0; g < 64; ++g) {
    float4 qv = e[g];
    if (qv.x >= T) {
      if (cnt < MAXC) cid[cnt++] = __builtin_bit_cast(int, qv.y);
      else smask |= 1ull << g;           // overflow candidate -> scan its whole group
    }
    if (qv.z >= T) smask |= 1ull << g;   // group 2nd-best in window -> scan whole group
  }
  idxf[row] = I1;  // exact when cnt==1 && smask==0
  int myitem = -1;
  if (cnt >= 2 || smask != 0ull) {
    unsigned s = atomicAdd(&flags[1], 1u);
    if (s < NROWS) {
      myitem = (int)s;
      int* o = items + (size_t)s * 20;
      o[0] = row; o[1] = cnt;
      o[2] = (int)(unsigned)(smask & 0xFFFFFFFFull);
      o[3] = (int)(unsigned)(smask >> 32);
#pragma unroll
      for (int c2 = 0; c2 < MAXC; ++c2) o[4 + c2] = (c2 < cnt) ? cid[c2] : 0;
    }
  }
  itemOf[row] = myitem;
}

// ---------------- f64 referee: (item, slot) work units; slot j scores codes j, j+8, ... ----------------
__global__ void groupscan_part(const float* __restrict__ z, const float* __restrict__ cb,
                               const int* __restrict__ items, const unsigned* __restrict__ flags,
                               double2* __restrict__ gpart) {
  const int lane = threadIdx.x & 63;
  const int gw = (blockIdx.x * 256 + threadIdx.x) >> 6;
  const int nwaves = gridDim.x * 4;
  unsigned n = flags[1];
  if (n > (unsigned)NROWS) n = NROWS;
  const unsigned tot = n * 8u;
  for (unsigned u = gw; u < tot; u += nwaves) {
    const unsigned it = u >> 3;
    const int slot = (int)(u & 7u);
    const int* en = items + (size_t)it * 20;
    const int row = en[0], cnt = en[1];
    const unsigned long long smask = ((unsigned long long)(unsigned)en[3] << 32) | (unsigned)en[2];
    const int total = cnt + 64 * __popcll(smask);
    double bs = -1e300; int bi = 1 << 30;
    if (slot < total) {
      const float* zr = z + (size_t)row * DIM + lane * 8;
      double zv[8];
#pragma unroll
      for (int j = 0; j < 8; ++j) zv[j] = (double)zr[j];
      auto code_at = [&](int w) -> int {
        if (w < cnt) return en[4 + w];
        const int qq = w - cnt;
        const int gsel = qq >> 6, o = qq & 63;
        unsigned long long m = smask;
        for (int i = 0; i < gsel; ++i) m &= m - 1;
        return grp_code(grp_base((int)__builtin_ctzll(m)), o);
      };
      auto score2 = [&](int k0, int k1) {  // two codes with ILP; k1<0 -> single
        const float* c0 = cb + (size_t)k0 * DIM + lane * 8;
        const float* c1 = cb + (size_t)((k1 < 0) ? k0 : k1) * DIM + lane * 8;
        double d0 = 0, n0 = 0, d1 = 0, n1 = 0;
#pragma unroll
        for (int j = 0; j < 8; ++j) {
          double a = c0[j]; d0 += zv[j] * a; n0 += a * a;
          double b = c1[j]; d1 += zv[j] * b; n1 += b * b;
        }
#pragma unroll
        for (int off = 1; off < 64; off <<= 1) {
          d0 += __shfl_xor(d0, off); n0 += __shfl_xor(n0, off);
          d1 += __shfl_xor(d1, off); n1 += __shfl_xor(n1, off);
        }
        double s0 = d0 / sqrt(n0);  // z-norm omitted: row-constant scale, argmax-invariant
        if (s0 > bs || (s0 == bs && k0 < bi)) { bs = s0; bi = k0; }
        if (k1 >= 0) {
          double s1 = d1 / sqrt(n1);
          if (s1 > bs || (s1 == bs && k1 < bi)) { bs = s1; bi = k1; }
        }
      };
      int w = slot;
      while (w < total) {
        const int k0 = code_at(w); w += 8;
        const int k1 = (w < total) ? code_at(w) : -1; w += 8;
        score2(k0, k1);
      }
    }
    if (lane == 0) gpart[u] = make_double2(bs, (double)bi);
  }
}

// ---------------- gather + straight-through + partial losses (+ inline 8-slot referee merge) ----------------
__global__ void outputs_kernel(const float* __restrict__ z, const float* __restrict__ cb,
                               const unsigned char* __restrict__ mask8, const int* __restrict__ mask32,
                               const unsigned* __restrict__ flags, const int* __restrict__ idxf,
                               const int* __restrict__ itemOf, const double2* __restrict__ gpart,
                               float* __restrict__ out, unsigned* __restrict__ counts,
                               double* __restrict__ cpart) {
  __shared__ double wsum[4];
  const int wv = threadIdx.x >> 6, lane = threadIdx.x & 63;
  const int row = blockIdx.x * 4 + wv;
  int idx = idxf[row];
  const int it = itemOf[row];
  if (it >= 0) {  // merge 8 slot-bests (uniform across lanes; L2-hot 128B)
    double bs = -1e300; int bi = 1 << 30;
#pragma unroll
    for (int s2 = 0; s2 < 8; ++s2) {
      double2 e = gpart[(size_t)it * 8 + s2];
      const int k = (int)e.y;
      if (e.x > bs || (e.x == bs && k < bi)) { bs = e.x; bi = k; }
    }
    if (bi < NCODES) idx = bi;
  }
  idx = (idx < 0) ? 0 : ((idx > NCODES - 1) ? NCODES - 1 : idx);  // defensive clamp
  const int mi = flags[0] ? (mask32[row] != 0) : (mask8[row] != 0);
  const float mf = mi ? 1.0f : 0.0f;
  const float* zr = z + (size_t)row * DIM;
  const float* cr = cb + (size_t)idx * DIM;
  double cs = 0.0;
#pragma unroll
  for (int h = 0; h < 2; ++h) {
    const int j = h * 256 + lane * 4;
    f32x4_t c  = *(const f32x4_t*)(cr + j);
    f32x4_t ze = *(const f32x4_t*)(zr + j);
    f32x4_t zq, zs;
#pragma unroll
    for (int e = 0; e < 4; ++e) {
      float qv = c[e] * mf;
      float d = qv - ze[e];
      zq[e] = qv;
      zs[e] = ze[e] + d;
      cs += (double)(d * d) * mf;
    }
    *(f32x4_t*)(out + OUT_ZQ   + (size_t)row * DIM + j) = zq;
    *(f32x4_t*)(out + OUT_ZQST + (size_t)row * DIM + j) = zs;
  }
#pragma unroll
  for (int off = 32; off; off >>= 1) cs += __shfl_down(cs, off);
  if (lane == 0) {
    wsum[wv] = cs;
    out[OUT_IDX + row] = (float)idx;
    if (mi) atomicAdd(&counts[idx], 1u);
  }
  __syncthreads();
  if (threadIdx.x == 0) cpart[blockIdx.x] = wsum[0] + wsum[1] + wsum[2] + wsum[3];
}

// ---------------- scalars ----------------
__global__ void finalize_kernel(const double* __restrict__ cpart, const unsigned* __restrict__ counts,
                                float* __restrict__ out) {
  __shared__ double sd[256];
  const int t = threadIdx.x;
  double s = 0;
  for (int i = t; i < 4096; i += 256) s += cpart[i];
  sd[t] = s; __syncthreads();
  for (int off = 128; off; off >>= 1) { if (t < off) sd[t] += sd[t + off]; __syncthreads(); }
  const double commit_sum = sd[0];
  __syncthreads();
  double c = 0;
  for (int i = t; i < 4096; i += 256) c += (double)counts[i];
  sd[t] = c; __syncthreads();
  for (int off = 128; off; off >>= 1) { if (t < off) sd[t] += sd[t + off]; __syncthreads(); }
  const double totc = sd[0];
  __syncthreads();
  const double denom = totc + 1e-5;
  double ent = 0;
  for (int i = t; i < 4096; i += 256) {
    double p = (double)counts[i] / denom;
    ent -= p * log(p + 1e-5);
  }
  sd[t] = ent; __syncthreads();
  for (int off = 128; off; off >>= 1) { if (t < off) sd[t] += sd[t + off]; __syncthreads(); }
  if (t == 0) {
    const double valid = fmax(totc, 1.0);
    const double commitment = commit_sum / valid;
    out[OUT_VQ]     = (float)(0.25 * commitment);
    out[OUT_COMMIT] = (float)commitment;
    out[OUT_PERP]   = (float)exp(sd[0]);
  }
}

extern "C" void kernel_launch(void* const* d_in, const int* in_sizes, int n_in,
                              void* d_out, int out_size, void* d_ws, size_t ws_size,
                              hipStream_t stream) {
  const float* z  = (const float*)d_in[0];
  const void*  mk = d_in[1];
  const float* cb = (const float*)d_in[2];
  float* out = (float*)d_out;
  char* ws = (char*)d_ws;

  unsigned char* Aws    = (unsigned char*)(ws + WS_A);
  unsigned char* Bws    = (unsigned char*)(ws + WS_B);
  float4*        topE   = (float4*)(ws + WS_TOPE);
  unsigned*      counts = (unsigned*)(ws + WS_COUNTS);
  unsigned*      flags  = (unsigned*)(ws + WS_FLAGS);
  int*           idxf   = (int*)(ws + WS_IDX);
  int*           items  = (int*)(ws + WS_ITEMS);
  double*        cpart  = (double*)(ws + WS_CPART);
  double2*       gpart  = (double2*)(ws + WS_GPART);
  int*           itemOf = (int*)(ws + WS_ITEMOF);

  prep_kernel<<<(NROWS + NCODES) / 4, 256, 0, stream>>>(z, cb, (const uint4*)mk, Aws, Bws,
                                                        counts, flags);
  gemm_p1_kernel<<<1024, 256, 0, stream>>>(Aws, Bws, topE);
  resolve_kernel<<<NROWS / 256, 256, 0, stream>>>(topE, idxf, items, itemOf, flags);
  groupscan_part<<<2048, 256, 0, stream>>>(z, cb, items, flags, gpart);
  outputs_kernel<<<NROWS / 4, 256, 0, stream>>>(z, cb, (const unsigned char*)mk, (const int*)mk,
                                                flags, idxf, itemOf, gpart, out, counts, cpart);
  finalize_kernel<<<1, 256, 0, stream>>>(cpart, counts, out);
}

// Round 23
// 271.451 us; speedup vs baseline: 1.4995x; 1.4995x over previous
//
#include <hip/hip_runtime.h>

typedef __attribute__((ext_vector_type(4))) float f32x4_t;
typedef __attribute__((ext_vector_type(8))) short bf16x8_t;

#define NROWS 16384
#define NCODES 4096
#define DIM 512
#define DELTA 0.005f     // > worst-case |f64 referee - hi-only bf16 pass1| = 0.0040
#define MAXC 16          // explicit candidate cap per row (overflow -> group bit)

// ---------------- workspace byte offsets (~41.5 MB; harness provides >=45.6 MB, proven round 4) ----------------
#define WS_A      0u          // 128 tb x 8 st x 16KB (BK=64 stages) -> 16777216
#define WS_B      16777216u   //  32 ct x 8 st x 16KB -> 20971520
#define WS_TOPE   20971520u   // [row 16384][grp 64] float4 -> 37748736
#define WS_COUNTS 37748736u   // 4096 u32 -> 37765120
#define WS_FLAGS  37765120u   // [0]=mask-layout [1]=item_cnt -> +64
#define WS_IDX    37765184u   // 16384 i32 -> 37830720
#define WS_ITEMS  37830720u   // 16384 x 20 i32 {row,cnt,maskLo,maskHi,cid[16]} -> 39141440
#define WS_CPART  39206976u   // 4096 f64 -> 39239744
#define WS_GPART  39239744u   // 16384 x 8 double2 -> 41336896
#define WS_ITEMOF 41336896u   // 16384 i32 -> 41402432

// output element offsets (flat f32)
#define OUT_ZQ      0
#define OUT_ZQST    8388608
#define OUT_IDX     16777216
#define OUT_VQ      16793600
#define OUT_COMMIT  16793601
#define OUT_PERP    16793602

__device__ __forceinline__ unsigned short f2bf(float x) {
  unsigned u = __builtin_bit_cast(unsigned, x);
  unsigned r = (u + 0x7FFFu + ((u >> 16) & 1u)) >> 16;  // RNE
  return (unsigned short)r;
}
__device__ __forceinline__ unsigned hz(unsigned x) {
  return (x - 0x01010101u) & ~x & 0x80808080u;  // any zero byte
}
// BK=64 stage layout: row r in [0,128) is 128B (8 x 16B units); XOR keeps ds_read banks 2-way (free)
__device__ __forceinline__ unsigned swz64(int r, int u) {
  return (unsigned)(r * 128 + ((u ^ (r & 7)) << 4));
}
// group g (0..63) -> base code; within-group offset o (0..63) -> code
__device__ __forceinline__ int grp_base(int g) {
  return (g >> 3) * 512 + ((g >> 2) & 1) * 64 + (g & 3) * 4;  // cg*512 + wc*64 + lrg*4
}
__device__ __forceinline__ int grp_code(int cbase, int o) {
  return cbase + (o >> 4) * 128 + ((o >> 2) & 3) * 16 + (o & 3);  // + ct*128 + n*16 + l
}

// ---------------- prep: zero counts/flags + mask probe + norms + bf16-hi convert into swizzled chunks ----------------
__global__ void prep_kernel(const float* __restrict__ z, const float* __restrict__ cb,
                            const uint4* __restrict__ mk,
                            unsigned char* __restrict__ Aws, unsigned char* __restrict__ Bws,
                            unsigned* __restrict__ counts, unsigned* __restrict__ flags) {
  if (blockIdx.x < 16) {
    counts[blockIdx.x * 256 + threadIdx.x] = 0;  // 4096 counts
  }
  if (blockIdx.x == 0) {
    if (threadIdx.x < 4) flags[threadIdx.x] = 0;
    __syncthreads();
    unsigned f = 0;
    for (int i = threadIdx.x; i < 1024; i += 256) {  // first 16KB of mask
      uint4 v = mk[i];
      f |= hz(v.x) | hz(v.y) | hz(v.z) | hz(v.w);
    }
    if (f) atomicOr(&flags[0], 1u);  // zero byte found -> int32 mask layout
  }
  const int wv = threadIdx.x >> 6, lane = threadIdx.x & 63;
  const int row = blockIdx.x * 4 + wv;
  if (row >= NROWS + NCODES) return;
  const bool isA = row < NROWS;
  const int lrow = isA ? row : row - NROWS;
  const float* src = (isA ? z : cb) + (size_t)lrow * DIM;
  f32x4_t a = *(const f32x4_t*)(src + lane * 8);
  f32x4_t b = *(const f32x4_t*)(src + lane * 8 + 4);
  double s = 0.0;
#pragma unroll
  for (int e = 0; e < 4; ++e) s += (double)a[e] * a[e] + (double)b[e] * b[e];
#pragma unroll
  for (int off = 1; off < 64; off <<= 1) s += __shfl_xor(s, off);
  const float inv = (float)(1.0 / fmax(sqrt(s), 1e-8));
  union { unsigned short u[8]; uint4 v; } H;
#pragma unroll
  for (int e = 0; e < 4; ++e) {
    H.u[e] = f2bf(a[e] * inv);
    H.u[4 + e] = f2bf(b[e] * inv);
  }
  const int tb = lrow >> 7, rr = lrow & 127;
  const int st = lane >> 3, u = lane & 7;  // stage = 64 cols, unit = 8 cols
  unsigned char* chunk = (isA ? Aws : Bws) + ((size_t)tb * 8 + st) * 16384;
  *(uint4*)(chunk + swz64(rr, u)) = H.v;
}

// ---------------- pass-1 GEMM: BK=64 single-buffer; per-lane top-2 + LDS-staged coalesced topE write ----------------
__global__ __launch_bounds__(256, 4) void gemm_p1_kernel(
    const unsigned char* __restrict__ Aws, const unsigned char* __restrict__ Bws,
    float4* __restrict__ topE) {
  __align__(16) __shared__ unsigned char smem[32768];  // staging (A 16K | B 16K); reused for topE stage

  const int tid = threadIdx.x;
  const int bid = blockIdx.x;
  const int xcd = bid & 7, q0 = bid >> 3;
  const int rb = xcd * 16 + (q0 >> 3), cg = q0 & 7;  // XCD-aware: 8 cg-blocks of one rb share an XCD L2
  const int wave = tid >> 6, lane = tid & 63;
  const int wr = wave >> 1, wc = wave & 1;
  const int kg = lane >> 4, lr = lane & 15;

  const unsigned char* Ach = Aws + (size_t)rb * 8 * 16384;

  auto issue_stage = [&](const unsigned char* Asrc, const unsigned char* Bsrc) {
#pragma unroll
    for (int i = 0; i < 8; ++i) {
      const int j = wave * 8 + i;  // 32 x 1KB units: A 0-15 -> lds 0-16K, B 16-31 -> lds 16-32K
      const unsigned char* sp = (j < 16) ? (Asrc + (size_t)j * 1024 + lane * 16)
                                         : (Bsrc + (size_t)(j - 16) * 1024 + lane * 16);
      __builtin_amdgcn_global_load_lds(
          (const __attribute__((address_space(1))) void*)sp,
          (__attribute__((address_space(3))) void*)(smem + j * 1024), 16, 0, 0);
    }
  };

  // per-lane running top-2 over the lane's 16 codes per (m,j): 48 VGPRs, static indexing only
  float tv1[16], tv2[16]; int ti1[16];
#pragma unroll
  for (int q = 0; q < 16; ++q) { tv1[q] = -3e38f; tv2[q] = -3e38f; ti1[q] = 0; }

  for (int ct = 0; ct < 4; ++ct) {
    const int ctile = cg * 4 + ct;
    const int code0 = ctile * 128;
    const unsigned char* Bch = Bws + (size_t)ctile * 8 * 16384;

    f32x4_t acc[4][4];
#pragma unroll
    for (int m = 0; m < 4; ++m)
#pragma unroll
      for (int n = 0; n < 4; ++n) acc[m][n] = (f32x4_t){0.f, 0.f, 0.f, 0.f};

    for (int st = 0; st < 8; ++st) {
      if (!(st == 0 && ct > 0))  // ct>0 stage-0 was pre-issued before previous insertion block
        issue_stage(Ach + (size_t)st * 16384, Bch + (size_t)st * 16384);
      __syncthreads();  // compiler drains vmcnt before barrier (m97 pattern)

#pragma unroll
      for (int kk = 0; kk < 2; ++kk) {  // two 32-col halves; frags scoped to stay in budget
        bf16x8_t ah[4], bh[4];
        const int u = kk * 4 + kg;
#pragma unroll
        for (int m = 0; m < 4; ++m) {
          const int r = wr * 64 + m * 16 + lr;
          ah[m] = *(const bf16x8_t*)(smem + swz64(r, u));
        }
#pragma unroll
        for (int n = 0; n < 4; ++n) {
          const int r = wc * 64 + n * 16 + lr;
          bh[n] = *(const bf16x8_t*)(smem + 16384 + swz64(r, u));
        }
#pragma unroll
        for (int m = 0; m < 4; ++m)
#pragma unroll
          for (int n = 0; n < 4; ++n)
            acc[m][n] = __builtin_amdgcn_mfma_f32_16x16x32_bf16(ah[m], bh[n], acc[m][n], 0, 0, 0);
      }
      __syncthreads();  // reads done before next stage overwrites
    }

    // pre-issue next ct's first stage: latency hides under the insertion block below
    if (ct < 3)
      issue_stage(Ach, Bws + (size_t)(ctile + 1) * 8 * 16384);

    // cheap per-lane insertion (no shuffles, no barriers): ascending code order keeps np ties
#pragma unroll
    for (int m = 0; m < 4; ++m)
#pragma unroll
      for (int j = 0; j < 4; ++j) {
        const int q = m * 4 + j;
#pragma unroll
        for (int n = 0; n < 4; ++n) {
          float v = acc[m][n][j];
          int gc = code0 + wc * 64 + n * 16 + lr;
          if (v > tv1[q]) { tv2[q] = tv1[q]; tv1[q] = v; ti1[q] = gc; }
          else if (v > tv2[q]) tv2[q] = v;
        }
      }
  }

  // single 2-step butterfly -> exact top-2 per (row, cg, wc, lr>>2); stage into LDS (smem is dead now)
  float4* stop = (float4*)smem;  // [lrow 128][e 8] = 16KB
#pragma unroll
  for (int m = 0; m < 4; ++m)
#pragma unroll
    for (int j = 0; j < 4; ++j) {
      const int q = m * 4 + j;
      float v1 = tv1[q], v2 = tv2[q]; int i1 = ti1[q];
#pragma unroll
      for (int mask = 1; mask <= 2; mask <<= 1) {
        float ov1 = __shfl_xor(v1, mask); int oi1 = __shfl_xor(i1, mask);
        float ov2 = __shfl_xor(v2, mask);
        bool of = (ov1 > v1) || (ov1 == v1 && oi1 < i1);
        float w1 = of ? ov1 : v1;  int k1 = of ? oi1 : i1;
        float lv = of ? v1 : ov1;  // loser's top-1
        float sv = of ? ov2 : v2;  // winner's top-2
        v1 = w1; i1 = k1;
        v2 = (lv > sv) ? lv : sv;  // v2 magnitude only (bounds unreported codes)
      }
      if ((lr & 3) == 0) {
        const int lrow = wr * 64 + m * 16 + kg * 4 + j;
        stop[lrow * 8 + wc * 4 + (lr >> 2)] =
            make_float4(v1, __builtin_bit_cast(float, i1), v2, 0.f);
      }
    }
  __syncthreads();
  // coalesced copy: 1024 float4 entries; thread t writes 4 consecutive (64B) -> full-line stores
#pragma unroll
  for (int i = 0; i < 4; ++i) {
    const int idx = tid * 4 + i;
    const int lrow = idx >> 3, e = idx & 7;
    topE[(size_t)(rb * 128 + lrow) * 64 + cg * 8 + e] = stop[idx];
  }
}

// ---------------- resolve: classify rows into {direct, referee item} (thread per row) ----------------
__global__ void resolve_kernel(const float4* __restrict__ topE, int* __restrict__ idxf,
                               int* __restrict__ items, int* __restrict__ itemOf,
                               unsigned* __restrict__ flags) {
  const int row = blockIdx.x * 256 + threadIdx.x;
  if (row >= NROWS) return;
  const float4* e = topE + (size_t)row * 64;
  float V1 = -3e38f; int I1 = 1 << 30;
  for (int g = 0; g < 64; ++g) {  // groups not code-ascending -> explicit index tie-break (np)
    float4 qv = e[g];
    const int i = __builtin_bit_cast(int, qv.y);
    if (qv.x > V1 || (qv.x == V1 && i < I1)) { V1 = qv.x; I1 = i; }
  }
  const float T = V1 - 2.0f * DELTA;
  unsigned long long smask = 0ull;  // suspect groups: their top-2 may hide a 3rd candidate
  int cnt = 0; int cid[MAXC];
  for (int g = 0; g < 64; ++g) {
    float4 qv = e[g];
    if (qv.x >= T) {
      if (cnt < MAXC) cid[cnt++] = __builtin_bit_cast(int, qv.y);
      else smask |= 1ull << g;           // overflow candidate -> scan its whole group
    }
    if (qv.z >= T) smask |= 1ull << g;   // group 2nd-best in window -> scan whole group
  }
  idxf[row] = I1;  // exact when cnt==1 && smask==0
  int myitem = -1;
  if (cnt >= 2 || smask != 0ull) {
    unsigned s = atomicAdd(&flags[1], 1u);
    if (s < NROWS) {
      myitem = (int)s;
      int* o = items + (size_t)s * 20;
      o[0] = row; o[1] = cnt;
      o[2] = (int)(unsigned)(smask & 0xFFFFFFFFull);
      o[3] = (int)(unsigned)(smask >> 32);
#pragma unroll
      for (int c2 = 0; c2 < MAXC; ++c2) o[4 + c2] = (c2 < cnt) ? cid[c2] : 0;
    }
  }
  itemOf[row] = myitem;
}

// ---------------- f64 referee: (item, slot) work units; slot j scores codes j, j+8, ... ----------------
__global__ void groupscan_part(const float* __restrict__ z, const float* __restrict__ cb,
                               const int* __restrict__ items, const unsigned* __restrict__ flags,
                               double2* __restrict__ gpart) {
  const int lane = threadIdx.x & 63;
  const int gw = (blockIdx.x * 256 + threadIdx.x) >> 6;
  const int nwaves = gridDim.x * 4;
  unsigned n = flags[1];
  if (n > (unsigned)NROWS) n = NROWS;
  const unsigned tot = n * 8u;
  for (unsigned u = gw; u < tot; u += nwaves) {
    const unsigned it = u >> 3;
    const int slot = (int)(u & 7u);
    const int* en = items + (size_t)it * 20;
    const int row = en[0], cnt = en[1];
    const unsigned long long smask = ((unsigned long long)(unsigned)en[3] << 32) | (unsigned)en[2];
    const int total = cnt + 64 * __popcll(smask);
    double bs = -1e300; int bi = 1 << 30;
    if (slot < total) {
      const float* zr = z + (size_t)row * DIM + lane * 8;
      double zv[8];
#pragma unroll
      for (int j = 0; j < 8; ++j) zv[j] = (double)zr[j];
      auto code_at = [&](int w) -> int {
        if (w < cnt) return en[4 + w];
        const int qq = w - cnt;
        const int gsel = qq >> 6, o = qq & 63;
        unsigned long long m = smask;
        for (int i = 0; i < gsel; ++i) m &= m - 1;
        return grp_code(grp_base((int)__builtin_ctzll(m)), o);
      };
      auto score2 = [&](int k0, int k1) {  // two codes with ILP; k1<0 -> single
        const float* c0 = cb + (size_t)k0 * DIM + lane * 8;
        const float* c1 = cb + (size_t)((k1 < 0) ? k0 : k1) * DIM + lane * 8;
        double d0 = 0, n0 = 0, d1 = 0, n1 = 0;
#pragma unroll
        for (int j = 0; j < 8; ++j) {
          double a = c0[j]; d0 += zv[j] * a; n0 += a * a;
          double b = c1[j]; d1 += zv[j] * b; n1 += b * b;
        }
#pragma unroll
        for (int off = 1; off < 64; off <<= 1) {
          d0 += __shfl_xor(d0, off); n0 += __shfl_xor(n0, off);
          d1 += __shfl_xor(d1, off); n1 += __shfl_xor(n1, off);
        }
        double s0 = d0 / sqrt(n0);  // z-norm omitted: row-constant scale, argmax-invariant
        if (s0 > bs || (s0 == bs && k0 < bi)) { bs = s0; bi = k0; }
        if (k1 >= 0) {
          double s1 = d1 / sqrt(n1);
          if (s1 > bs || (s1 == bs && k1 < bi)) { bs = s1; bi = k1; }
        }
      };
      int w = slot;
      while (w < total) {
        const int k0 = code_at(w); w += 8;
        const int k1 = (w < total) ? code_at(w) : -1; w += 8;
        score2(k0, k1);
      }
    }
    if (lane == 0) gpart[u] = make_double2(bs, (double)bi);
  }
}

// ---------------- gather + straight-through + partial losses (+ inline 8-slot referee merge) ----------------
__global__ void outputs_kernel(const float* __restrict__ z, const float* __restrict__ cb,
                               const unsigned char* __restrict__ mask8, const int* __restrict__ mask32,
                               const unsigned* __restrict__ flags, const int* __restrict__ idxf,
                               const int* __restrict__ itemOf, const double2* __restrict__ gpart,
                               float* __restrict__ out, unsigned* __restrict__ counts,
                               double* __restrict__ cpart) {
  __shared__ double wsum[4];
  const int wv = threadIdx.x >> 6, lane = threadIdx.x & 63;
  const int row = blockIdx.x * 4 + wv;
  int idx = idxf[row];
  const int it = itemOf[row];
  if (it >= 0) {  // merge 8 slot-bests (uniform across lanes; L2-hot 128B)
    double bs = -1e300; int bi = 1 << 30;
#pragma unroll
    for (int s2 = 0; s2 < 8; ++s2) {
      double2 e = gpart[(size_t)it * 8 + s2];
      const int k = (int)e.y;
      if (e.x > bs || (e.x == bs && k < bi)) { bs = e.x; bi = k; }
    }
    if (bi < NCODES) idx = bi;
  }
  idx = (idx < 0) ? 0 : ((idx > NCODES - 1) ? NCODES - 1 : idx);  // defensive clamp
  const int mi = flags[0] ? (mask32[row] != 0) : (mask8[row] != 0);
  const float mf = mi ? 1.0f : 0.0f;
  const float* zr = z + (size_t)row * DIM;
  const float* cr = cb + (size_t)idx * DIM;
  double cs = 0.0;
#pragma unroll
  for (int h = 0; h < 2; ++h) {
    const int j = h * 256 + lane * 4;
    f32x4_t c  = *(const f32x4_t*)(cr + j);
    f32x4_t ze = *(const f32x4_t*)(zr + j);
    f32x4_t zq, zs;
#pragma unroll
    for (int e = 0; e < 4; ++e) {
      float qv = c[e] * mf;
      float d = qv - ze[e];
      zq[e] = qv;
      zs[e] = ze[e] + d;
      cs += (double)(d * d) * mf;
    }
    *(f32x4_t*)(out + OUT_ZQ   + (size_t)row * DIM + j) = zq;
    *(f32x4_t*)(out + OUT_ZQST + (size_t)row * DIM + j) = zs;
  }
#pragma unroll
  for (int off = 32; off; off >>= 1) cs += __shfl_down(cs, off);
  if (lane == 0) {
    wsum[wv] = cs;
    out[OUT_IDX + row] = (float)idx;
    if (mi) atomicAdd(&counts[idx], 1u);
  }
  __syncthreads();
  if (threadIdx.x == 0) cpart[blockIdx.x] = wsum[0] + wsum[1] + wsum[2] + wsum[3];
}

// ---------------- scalars ----------------
__global__ void finalize_kernel(const double* __restrict__ cpart, const unsigned* __restrict__ counts,
                                float* __restrict__ out) {
  __shared__ double sd[256];
  const int t = threadIdx.x;
  double s = 0;
  for (int i = t; i < 4096; i += 256) s += cpart[i];
  sd[t] = s; __syncthreads();
  for (int off = 128; off; off >>= 1) { if (t < off) sd[t] += sd[t + off]; __syncthreads(); }
  const double commit_sum = sd[0];
  __syncthreads();
  double c = 0;
  for (int i = t; i < 4096; i += 256) c += (double)counts[i];
  sd[t] = c; __syncthreads();
  for (int off = 128; off; off >>= 1) { if (t < off) sd[t] += sd[t + off]; __syncthreads(); }
  const double totc = sd[0];
  __syncthreads();
  const double denom = totc + 1e-5;
  double ent = 0;
  for (int i = t; i < 4096; i += 256) {
    double p = (double)counts[i] / denom;
    ent -= p * log(p + 1e-5);
  }
  sd[t] = ent; __syncthreads();
  for (int off = 128; off; off >>= 1) { if (t < off) sd[t] += sd[t + off]; __syncthreads(); }
  if (t == 0) {
    const double valid = fmax(totc, 1.0);
    const double commitment = commit_sum / valid;
    out[OUT_VQ]     = (float)(0.25 * commitment);
    out[OUT_COMMIT] = (float)commitment;
    out[OUT_PERP]   = (float)exp(sd[0]);
  }
}

extern "C" void kernel_launch(void* const* d_in, const int* in_sizes, int n_in,
                              void* d_out, int out_size, void* d_ws, size_t ws_size,
                              hipStream_t stream) {
  const float* z  = (const float*)d_in[0];
  const void*  mk = d_in[1];
  const float* cb = (const float*)d_in[2];
  float* out = (float*)d_out;
  char* ws = (char*)d_ws;

  unsigned char* Aws    = (unsigned char*)(ws + WS_A);
  unsigned char* Bws    = (unsigned char*)(ws + WS_B);
  float4*        topE   = (float4*)(ws + WS_TOPE);
  unsigned*      counts = (unsigned*)(ws + WS_COUNTS);
  unsigned*      flags  = (unsigned*)(ws + WS_FLAGS);
  int*           idxf   = (int*)(ws + WS_IDX);
  int*           items  = (int*)(ws + WS_ITEMS);
  double*        cpart  = (double*)(ws + WS_CPART);
  double2*       gpart  = (double2*)(ws + WS_GPART);
  int*           itemOf = (int*)(ws + WS_ITEMOF);

  prep_kernel<<<(NROWS + NCODES) / 4, 256, 0, stream>>>(z, cb, (const uint4*)mk, Aws, Bws,
                                                        counts, flags);
  gemm_p1_kernel<<<1024, 256, 0, stream>>>(Aws, Bws, topE);
  resolve_kernel<<<NROWS / 256, 256, 0, stream>>>(topE, idxf, items, itemOf, flags);
  groupscan_part<<<2048, 256, 0, stream>>>(z, cb, items, flags, gpart);
  outputs_kernel<<<NROWS / 4, 256, 0, stream>>>(z, cb, (const unsigned char*)mk, (const int*)mk,
                                                flags, idxf, itemOf, gpart, out, counts, cpart);
  finalize_kernel<<<1, 256, 0, stream>>>(cpart, counts, out);
}